// Round 7
// baseline (138.445 us; speedup 1.0000x reference)
//
#include <hip/hip_runtime.h>

#define NODES 255
#define IN_DIM 512
#define ODIM 64
#define BM 64

typedef __attribute__((ext_vector_type(8))) short short8v;
typedef __attribute__((ext_vector_type(4))) float f32x4;
typedef unsigned short u16;
typedef unsigned int u32;

__device__ __forceinline__ u16 f32_bf16(float f) {
  u32 u = __builtin_bit_cast(u32, f);
  u += 0x7FFFu + ((u >> 16) & 1u);
  return (u16)(u >> 16);
}
__device__ __forceinline__ float bf16_f32(u16 h) {
  u32 u = ((u32)h) << 16;
  return __builtin_bit_cast(float, u);
}

// Fragment-linear pre-split (same as R5):
//  W: frag(kc 0..15, nb 0..15): elem(lane,j) = W[node=nb*16+(lane&15)][k=kc*32+(lane>>4)*8+j]
//     at linear ((kc*16+nb)*64+lane)*8+j
//  AT: frag(kc4 0..7, nb 0..3): elem(lane,j) = A[leaf=kc4*32+(lane>>4)*8+j][col=nb*16+(lane&15)]
//     at linear ((kc4*4+nb)*64+lane)*8+j
__global__ __launch_bounds__(256) void prep_kernel(
    const float* __restrict__ layers, const float* __restrict__ aprobs,
    u16* __restrict__ Wfh, u16* __restrict__ Wfl,
    u16* __restrict__ ATfh, u16* __restrict__ ATfl) {
  int id = blockIdx.x * 256 + threadIdx.x;
  if (id < 131072) {
    const int j = id & 7;
    const int lane = (id >> 3) & 63;
    const int nb = (id >> 9) & 15;
    const int kc = id >> 13;
    const int node = nb * 16 + (lane & 15);
    const int k = kc * 32 + ((lane >> 4) << 3) + j;
    const float v = (node < NODES) ? layers[node * IN_DIM + k] : 0.f;
    const u16 h = f32_bf16(v);
    Wfh[id] = h;
    Wfl[id] = f32_bf16(v - bf16_f32(h));
  } else if (id < 131072 + 16384) {
    const int t = id - 131072;
    const int j = t & 7;
    const int lane = (t >> 3) & 63;
    const int nb = (t >> 9) & 3;
    const int kc4 = t >> 11;
    const int c = nb * 16 + (lane & 15);
    const int leaf = kc4 * 32 + ((lane >> 4) << 3) + j;
    const float v = aprobs[leaf * ODIM + c];
    const u16 h = f32_bf16(v);
    ATfh[t] = h;
    ATfl[t] = f32_bf16(v - bf16_f32(h));
  }
}

// 512 threads (8 waves), BM=64 rows/block, grid 512, 4 blocks/CU.
// LDS: one 33,792 B arena, time-shared:
//   phase 1 : x dbuf bf16 hi/lo (32 KB)
//   phase 2/3 (per 32-row half): s_sigT f32[256][33]
//   phase 4 (per half): s_part f32[4][32][65] (33,280 B)
__global__ __launch_bounds__(512, 8) void prolo_main(
    const float* __restrict__ x, const float* __restrict__ comp,
    const float* __restrict__ alpha,
    const u16* __restrict__ Wfh, const u16* __restrict__ Wfl,
    const u16* __restrict__ ATfh, const u16* __restrict__ ATfl,
    float* __restrict__ out) {
  __shared__ __align__(16) unsigned char smem[33792];
  float* s_sigT = (float*)smem;   // [256][33]
  float* s_part = (float*)smem;   // [4][32][65]
  u16* sX = (u16*)smem;           // dbuf: buf b hi at b*8192, lo at b*8192+4096 (u16)

  const int tid = threadIdx.x;
  const int lane = tid & 63;
  const int w = tid >> 6;
  const int l15 = lane & 15;
  const int lq = lane >> 4;
  const int row0 = blockIdx.x * BM;
  const float alphav = alpha[0];

  // comparators for phase 2
  const int col0 = (w << 5) + l15;
  const int col1 = col0 + 16;
  const float cv0 = (col0 < NODES) ? comp[col0] : 0.f;
  const float cv1 = (col1 < NODES) ? comp[col1] : 0.f;

  // ---------- Phase 1 (R5-proven): z GEMM. Wave w owns nodes [32w,32w+32), rows 0..63.
  f32x4 acc[4][2];
#pragma unroll
  for (int i = 0; i < 4; ++i)
#pragma unroll
    for (int j = 0; j < 2; ++j) acc[i][j] = {0.f, 0.f, 0.f, 0.f};

  const int srow = tid >> 3;            // staging row 0..63
  const int k0 = (tid & 7) << 3;        // staging k 0..56
  const int soff = srow * 64 + (k0 ^ ((srow & 7) << 3));
  const float* xbase = x + (size_t)(row0 + srow) * IN_DIM + k0;

  f32x4 vA0 = *reinterpret_cast<const f32x4*>(xbase);
  f32x4 vA1 = *reinterpret_cast<const f32x4*>(xbase + 4);
  f32x4 vB0 = *reinterpret_cast<const f32x4*>(xbase + 64);
  f32x4 vB1 = *reinterpret_cast<const f32x4*>(xbase + 68);

#define STAGE_CHUNK(P0, P1, BUF)                                              \
  {                                                                           \
    u32* dh = reinterpret_cast<u32*>(sX + (BUF)*8192 + soff);                 \
    u32* dl = reinterpret_cast<u32*>(sX + (BUF)*8192 + 4096 + soff);          \
    float ff[8] = {P0[0], P0[1], P0[2], P0[3], P1[0], P1[1], P1[2], P1[3]};   \
    _Pragma("unroll") for (int j = 0; j < 4; ++j) {                           \
      u16 ha = f32_bf16(ff[2 * j]), hb = f32_bf16(ff[2 * j + 1]);             \
      u16 la = f32_bf16(ff[2 * j] - bf16_f32(ha));                            \
      u16 lb = f32_bf16(ff[2 * j + 1] - bf16_f32(hb));                        \
      dh[j] = (u32)ha | ((u32)hb << 16);                                      \
      dl[j] = (u32)la | ((u32)lb << 16);                                      \
    }                                                                         \
  }

  const int wfbase = (w << 10) + (lane << 3);

#define COMPUTE(KS, BUF)                                                      \
  {                                                                           \
    short8v wbh[2][2], wbl[2][2];                                             \
    _Pragma("unroll") for (int kq = 0; kq < 2; ++kq) {                        \
      _Pragma("unroll") for (int ntl = 0; ntl < 2; ++ntl) {                   \
        const int fb = ((((KS) << 1) + kq) << 13) + wfbase + (ntl << 9);      \
        wbh[kq][ntl] = *reinterpret_cast<const short8v*>(Wfh + fb);           \
        wbl[kq][ntl] = *reinterpret_cast<const short8v*>(Wfl + fb);           \
      }                                                                       \
    }                                                                         \
    _Pragma("unroll") for (int kq = 0; kq < 2; ++kq) {                        \
      _Pragma("unroll") for (int mt = 0; mt < 4; ++mt) {                      \
        const int r = (mt << 4) + l15;                                        \
        const int kk = (kq << 5) + (lq << 3);                                 \
        const int aoff = r * 64 + (kk ^ ((r & 7) << 3));                      \
        const short8v ah = *reinterpret_cast<const short8v*>(sX + (BUF)*8192 + aoff);        \
        const short8v al = *reinterpret_cast<const short8v*>(sX + (BUF)*8192 + 4096 + aoff); \
        _Pragma("unroll") for (int ntl = 0; ntl < 2; ++ntl) {                 \
          acc[mt][ntl] = __builtin_amdgcn_mfma_f32_16x16x32_bf16(ah, wbh[kq][ntl], acc[mt][ntl], 0, 0, 0); \
          acc[mt][ntl] = __builtin_amdgcn_mfma_f32_16x16x32_bf16(ah, wbl[kq][ntl], acc[mt][ntl], 0, 0, 0); \
          acc[mt][ntl] = __builtin_amdgcn_mfma_f32_16x16x32_bf16(al, wbh[kq][ntl], acc[mt][ntl], 0, 0, 0); \
        }                                                                     \
      }                                                                       \
    }                                                                         \
  }

  STAGE_CHUNK(vA0, vA1, 0);
  __syncthreads();

#pragma unroll
  for (int ks = 0; ks < 8; ++ks) {
    if (ks + 2 < 8) {
      const float* xp = xbase + (ks + 2) * 64;
      vA0 = *reinterpret_cast<const f32x4*>(xp);
      vA1 = *reinterpret_cast<const f32x4*>(xp + 4);
    }
    if (ks + 1 < 8) STAGE_CHUNK(vB0, vB1, ((ks + 1) & 1));

    switch (ks) {
      case 0: COMPUTE(0, 0) break;
      case 1: COMPUTE(1, 1) break;
      case 2: COMPUTE(2, 0) break;
      case 3: COMPUTE(3, 1) break;
      case 4: COMPUTE(4, 0) break;
      case 5: COMPUTE(5, 1) break;
      case 6: COMPUTE(6, 0) break;
      case 7: COMPUTE(7, 1) break;
    }
    {
      f32x4 t0 = vA0, t1 = vA1;
      vA0 = vB0; vA1 = vB1;
      vB0 = t0;  vB1 = t1;
    }
    __syncthreads();
  }

  // ---------- Phases 2-5, two 32-row halves through the shared LDS arena.
  const int mth = w >> 2;       // phase-3 m-half tile (rows mth*16..+15 of the half)
  const int kh = w & 3;         // phase-3 K quarter (64 leaves)
  const int arow = (mth << 4) + l15;

#pragma unroll
  for (int half = 0; half < 2; ++half) {
    // ---- Phase 2: sigmoid((z-c)*alpha) -> s_sigT[node][rloc], rloc 0..31
#pragma unroll
    for (int mh = 0; mh < 2; ++mh) {
#pragma unroll
      for (int ntl = 0; ntl < 2; ++ntl) {
        const int col = (w << 5) + (ntl << 4) + l15;
        const float cv = ntl ? cv1 : cv0;
#pragma unroll
        for (int r4 = 0; r4 < 4; ++r4) {
          const int rloc = (mh << 4) + (lq << 2) + r4;
          const float z = (acc[(half << 1) + mh][ntl][r4] - cv) * alphav;
          s_sigT[col * 33 + rloc] = 1.f / (1.f + __expf(-z));
        }
      }
    }
    __syncthreads();

    // ---- Phase 3: tree leaf probs (in-register) -> p@A MFMA, K quarter kh.
    f32x4 acc2[4];
#pragma unroll
    for (int i = 0; i < 4; ++i) acc2[i] = {0.f, 0.f, 0.f, 0.f};

#define SV(node) s_sigT[(node) * 33 + arow]

#pragma unroll
    for (int ks = 0; ks < 2; ++ks) {
      const int lb = (kh << 6) + (ks << 5) + (lq << 3);
      float P = 1.f;
#pragma unroll
      for (int n = 0; n < 5; ++n) {
        const int node = (1 << n) - 1 + (lb >> (8 - n));
        const float s = SV(node);
        P *= ((lb >> (7 - n)) & 1) ? (1.f - s) : s;
      }
      const float s5 = SV(31 + (lb >> 3));
      const int n6 = 63 + (lb >> 2);
      const float s6a = SV(n6);
      const float s6b = SV(n6 + 1);
      const int n7 = 127 + (lb >> 1);
      const float s7_0 = SV(n7);
      const float s7_1 = SV(n7 + 1);
      const float s7_2 = SV(n7 + 2);
      const float s7_3 = SV(n7 + 3);
      const float q0 = P * s5, q1 = P - P * s5;
      const float r00 = q0 * s6a, r01 = q0 - q0 * s6a;
      const float r10 = q1 * s6b, r11 = q1 - q1 * s6b;
      float p[8];
      p[0] = r00 * s7_0; p[1] = r00 - p[0];
      p[2] = r01 * s7_1; p[3] = r01 - p[2];
      p[4] = r10 * s7_2; p[5] = r10 - p[4];
      p[6] = r11 * s7_3; p[7] = r11 - p[6];
      short8v pah, pal;
#pragma unroll
      for (int j = 0; j < 8; ++j) {
        const u16 h = f32_bf16(p[j]);
        pah[j] = (short)h;
        pal[j] = (short)f32_bf16(p[j] - bf16_f32(h));
      }
      const int ksg = (kh << 1) + ks;
#pragma unroll
      for (int nt = 0; nt < 4; ++nt) {
        const int fb = (((ksg << 2) + nt) << 9) + (lane << 3);
        const short8v bhv = *reinterpret_cast<const short8v*>(ATfh + fb);
        const short8v blv = *reinterpret_cast<const short8v*>(ATfl + fb);
        acc2[nt] = __builtin_amdgcn_mfma_f32_16x16x32_bf16(pah, bhv, acc2[nt], 0, 0, 0);
        acc2[nt] = __builtin_amdgcn_mfma_f32_16x16x32_bf16(pah, blv, acc2[nt], 0, 0, 0);
        acc2[nt] = __builtin_amdgcn_mfma_f32_16x16x32_bf16(pal, bhv, acc2[nt], 0, 0, 0);
      }
    }
    __syncthreads();  // s_sigT reads done

    // ---- Phase 4a: write K-quarter partials to s_part[kh][row][col] (pad 65)
#pragma unroll
    for (int nt = 0; nt < 4; ++nt)
#pragma unroll
      for (int r4 = 0; r4 < 4; ++r4)
        s_part[((kh << 5) + (mth << 4) + (lq << 2) + r4) * 65 + (nt << 4) + l15] = acc2[nt][r4];
    __syncthreads();

    // ---- Phase 4b+5: reduce 4 quarters, softmax, store. Thread row r = 4w+lq.
    {
      const int r = (w << 2) + lq;
      float v0 = 0.f, v1 = 0.f, v2 = 0.f, v3 = 0.f;
#pragma unroll
      for (int k2 = 0; k2 < 4; ++k2) {
        const float* pr = s_part + ((k2 << 5) + r) * 65 + l15;
        v0 += pr[0];
        v1 += pr[16];
        v2 += pr[32];
        v3 += pr[48];
      }
      float m = fmaxf(fmaxf(v0, v1), fmaxf(v2, v3));
#pragma unroll
      for (int d = 1; d < 16; d <<= 1) m = fmaxf(m, __shfl_xor(m, d, 64));
      float e0 = __expf(v0 - m), e1 = __expf(v1 - m), e2 = __expf(v2 - m), e3 = __expf(v3 - m);
      float ssum = e0 + e1 + e2 + e3;
#pragma unroll
      for (int d = 1; d < 16; d <<= 1) ssum += __shfl_xor(ssum, d, 64);
      const float inv = 1.f / ssum;
      float* op = out + (size_t)(row0 + (half << 5) + r) * ODIM + l15;
      op[0]  = e0 * inv;
      op[16] = e1 * inv;
      op[32] = e2 * inv;
      op[48] = e3 * inv;
    }
    __syncthreads();  // protect next half's s_sigT overwrite
  }
}

extern "C" void kernel_launch(void* const* d_in, const int* in_sizes, int n_in,
                              void* d_out, int out_size, void* d_ws, size_t ws_size,
                              hipStream_t stream) {
  const float* x      = (const float*)d_in[0];
  const float* layers = (const float*)d_in[1];
  const float* comp   = (const float*)d_in[2];
  const float* alpha  = (const float*)d_in[3];
  const float* aprobs = (const float*)d_in[4];
  float* out = (float*)d_out;

  const size_t wsplit = (size_t)131072;
  const size_t atsz   = (size_t)16384;
  if (ws_size < (2 * wsplit + 2 * atsz) * sizeof(u16)) return;

  u16* Wfh  = (u16*)d_ws;
  u16* Wfl  = Wfh + wsplit;
  u16* ATfh = Wfl + wsplit;
  u16* ATfl = ATfh + atsz;

  const int prep_items = 131072 + 16384;
  prep_kernel<<<dim3((prep_items + 255) / 256), dim3(256), 0, stream>>>(
      layers, aprobs, Wfh, Wfl, ATfh, ATfl);

  prolo_main<<<dim3(32768 / BM), dim3(512), 0, stream>>>(
      x, comp, alpha, Wfh, Wfl, ATfh, ATfl, out);
}

// Round 8
// 76.127 us; speedup vs baseline: 1.8186x; 1.8186x over previous
//
#include <hip/hip_runtime.h>

#define NODES 255
#define IN_DIM 512
#define ODIM 64
#define BM 64

typedef __attribute__((ext_vector_type(8))) short short8v;
typedef __attribute__((ext_vector_type(4))) float f32x4;
typedef unsigned short u16;
typedef unsigned int u32;

__device__ __forceinline__ u16 f32_bf16(float f) {
  u32 u = __builtin_bit_cast(u32, f);
  u += 0x7FFFu + ((u >> 16) & 1u);
  return (u16)(u >> 16);
}
__device__ __forceinline__ float bf16_f32(u16 h) {
  u32 u = ((u32)h) << 16;
  return __builtin_bit_cast(float, u);
}

// Fragment-linear pre-split (same as R5):
//  W: frag(kc 0..15, nb 0..15): elem(lane,j) = W[node=nb*16+(lane&15)][k=kc*32+(lane>>4)*8+j]
//     at linear ((kc*16+nb)*64+lane)*8+j
//  AT: frag(kc4 0..7, nb 0..3): elem(lane,j) = A[leaf=kc4*32+(lane>>4)*8+j][col=nb*16+(lane&15)]
//     at linear ((kc4*4+nb)*64+lane)*8+j
__global__ __launch_bounds__(256) void prep_kernel(
    const float* __restrict__ layers, const float* __restrict__ aprobs,
    u16* __restrict__ Wfh, u16* __restrict__ Wfl,
    u16* __restrict__ ATfh, u16* __restrict__ ATfl) {
  int id = blockIdx.x * 256 + threadIdx.x;
  if (id < 131072) {
    const int j = id & 7;
    const int lane = (id >> 3) & 63;
    const int nb = (id >> 9) & 15;
    const int kc = id >> 13;
    const int node = nb * 16 + (lane & 15);
    const int k = kc * 32 + ((lane >> 4) << 3) + j;
    const float v = (node < NODES) ? layers[node * IN_DIM + k] : 0.f;
    const u16 h = f32_bf16(v);
    Wfh[id] = h;
    Wfl[id] = f32_bf16(v - bf16_f32(h));
  } else if (id < 131072 + 16384) {
    const int t = id - 131072;
    const int j = t & 7;
    const int lane = (t >> 3) & 63;
    const int nb = (t >> 9) & 3;
    const int kc4 = t >> 11;
    const int c = nb * 16 + (lane & 15);
    const int leaf = kc4 * 32 + ((lane >> 4) << 3) + j;
    const float v = aprobs[leaf * ODIM + c];
    const u16 h = f32_bf16(v);
    ATfh[t] = h;
    ATfl[t] = f32_bf16(v - bf16_f32(h));
  }
}

// 512 threads (8 waves), BM=64 rows/block, grid 512, 3 blocks/CU (VGPR<=85).
// LDS: one 33,792 B arena, time-shared:
//   phase 1 : x dbuf bf16 hi/lo (32 KB)
//   phase 2/3 (per 32-row half): s_sigT f32[256][33]
//   phase 4 (per half): s_part f32[4][32][65] (33,280 B)
__global__ __launch_bounds__(512, 6) void prolo_main(
    const float* __restrict__ x, const float* __restrict__ comp,
    const float* __restrict__ alpha,
    const u16* __restrict__ Wfh, const u16* __restrict__ Wfl,
    const u16* __restrict__ ATfh, const u16* __restrict__ ATfl,
    float* __restrict__ out) {
  __shared__ __align__(16) unsigned char smem[33792];
  float* s_sigT = (float*)smem;   // [256][33]
  float* s_part = (float*)smem;   // [4][32][65]
  u16* sX = (u16*)smem;           // dbuf: buf b hi at b*8192, lo at b*8192+4096 (u16)

  const int tid = threadIdx.x;
  const int lane = tid & 63;
  const int w = tid >> 6;
  const int l15 = lane & 15;
  const int lq = lane >> 4;
  const int row0 = blockIdx.x * BM;
  const float alphav = alpha[0];

  // comparators for phase 2
  const int col0 = (w << 5) + l15;
  const int col1 = col0 + 16;
  const float cv0 = (col0 < NODES) ? comp[col0] : 0.f;
  const float cv1 = (col1 < NODES) ? comp[col1] : 0.f;

  // ---------- Phase 1 (R5-proven): z GEMM. Wave w owns nodes [32w,32w+32), rows 0..63.
  f32x4 acc[4][2];
#pragma unroll
  for (int i = 0; i < 4; ++i)
#pragma unroll
    for (int j = 0; j < 2; ++j) acc[i][j] = {0.f, 0.f, 0.f, 0.f};

  const int srow = tid >> 3;            // staging row 0..63
  const int k0 = (tid & 7) << 3;        // staging k 0..56
  const int soff = srow * 64 + (k0 ^ ((srow & 7) << 3));
  const float* xbase = x + (size_t)(row0 + srow) * IN_DIM + k0;

  f32x4 vA0 = *reinterpret_cast<const f32x4*>(xbase);
  f32x4 vA1 = *reinterpret_cast<const f32x4*>(xbase + 4);
  f32x4 vB0 = *reinterpret_cast<const f32x4*>(xbase + 64);
  f32x4 vB1 = *reinterpret_cast<const f32x4*>(xbase + 68);

#define STAGE_CHUNK(P0, P1, BUF)                                              \
  {                                                                           \
    u32* dh = reinterpret_cast<u32*>(sX + (BUF)*8192 + soff);                 \
    u32* dl = reinterpret_cast<u32*>(sX + (BUF)*8192 + 4096 + soff);          \
    float ff[8] = {P0[0], P0[1], P0[2], P0[3], P1[0], P1[1], P1[2], P1[3]};   \
    _Pragma("unroll") for (int j = 0; j < 4; ++j) {                           \
      u16 ha = f32_bf16(ff[2 * j]), hb = f32_bf16(ff[2 * j + 1]);             \
      u16 la = f32_bf16(ff[2 * j] - bf16_f32(ha));                            \
      u16 lb = f32_bf16(ff[2 * j + 1] - bf16_f32(hb));                        \
      dh[j] = (u32)ha | ((u32)hb << 16);                                      \
      dl[j] = (u32)la | ((u32)lb << 16);                                      \
    }                                                                         \
  }

  const int wfbase = (w << 10) + (lane << 3);

#define COMPUTE(KS, BUF)                                                      \
  {                                                                           \
    short8v wbh[2][2], wbl[2][2];                                             \
    _Pragma("unroll") for (int kq = 0; kq < 2; ++kq) {                        \
      _Pragma("unroll") for (int ntl = 0; ntl < 2; ++ntl) {                   \
        const int fb = ((((KS) << 1) + kq) << 13) + wfbase + (ntl << 9);      \
        wbh[kq][ntl] = *reinterpret_cast<const short8v*>(Wfh + fb);           \
        wbl[kq][ntl] = *reinterpret_cast<const short8v*>(Wfl + fb);           \
      }                                                                       \
    }                                                                         \
    _Pragma("unroll") for (int kq = 0; kq < 2; ++kq) {                        \
      _Pragma("unroll") for (int mt = 0; mt < 4; ++mt) {                      \
        const int r = (mt << 4) + l15;                                        \
        const int kk = (kq << 5) + (lq << 3);                                 \
        const int aoff = r * 64 + (kk ^ ((r & 7) << 3));                      \
        const short8v ah = *reinterpret_cast<const short8v*>(sX + (BUF)*8192 + aoff);        \
        const short8v al = *reinterpret_cast<const short8v*>(sX + (BUF)*8192 + 4096 + aoff); \
        _Pragma("unroll") for (int ntl = 0; ntl < 2; ++ntl) {                 \
          acc[mt][ntl] = __builtin_amdgcn_mfma_f32_16x16x32_bf16(ah, wbh[kq][ntl], acc[mt][ntl], 0, 0, 0); \
          acc[mt][ntl] = __builtin_amdgcn_mfma_f32_16x16x32_bf16(ah, wbl[kq][ntl], acc[mt][ntl], 0, 0, 0); \
          acc[mt][ntl] = __builtin_amdgcn_mfma_f32_16x16x32_bf16(al, wbh[kq][ntl], acc[mt][ntl], 0, 0, 0); \
        }                                                                     \
      }                                                                       \
    }                                                                         \
  }

  STAGE_CHUNK(vA0, vA1, 0);
  __syncthreads();

#pragma unroll
  for (int ks = 0; ks < 8; ++ks) {
    if (ks + 2 < 8) {
      const float* xp = xbase + (ks + 2) * 64;
      vA0 = *reinterpret_cast<const f32x4*>(xp);
      vA1 = *reinterpret_cast<const f32x4*>(xp + 4);
    }
    if (ks + 1 < 8) STAGE_CHUNK(vB0, vB1, ((ks + 1) & 1));

    switch (ks) {
      case 0: COMPUTE(0, 0) break;
      case 1: COMPUTE(1, 1) break;
      case 2: COMPUTE(2, 0) break;
      case 3: COMPUTE(3, 1) break;
      case 4: COMPUTE(4, 0) break;
      case 5: COMPUTE(5, 1) break;
      case 6: COMPUTE(6, 0) break;
      case 7: COMPUTE(7, 1) break;
    }
    {
      f32x4 t0 = vA0, t1 = vA1;
      vA0 = vB0; vA1 = vB1;
      vB0 = t0;  vB1 = t1;
    }
    __syncthreads();
  }

  // ---------- Phases 2-5, two 32-row halves through the shared LDS arena.
  const int mth = w >> 2;       // phase-3 m-half tile (rows mth*16..+15 of the half)
  const int kh = w & 3;         // phase-3 K quarter (64 leaves)
  const int arow = (mth << 4) + l15;

#pragma unroll
  for (int half = 0; half < 2; ++half) {
    // ---- Phase 2: sigmoid((z-c)*alpha) -> s_sigT[node][rloc], rloc 0..31
#pragma unroll
    for (int mh = 0; mh < 2; ++mh) {
#pragma unroll
      for (int ntl = 0; ntl < 2; ++ntl) {
        const int col = (w << 5) + (ntl << 4) + l15;
        const float cv = ntl ? cv1 : cv0;
#pragma unroll
        for (int r4 = 0; r4 < 4; ++r4) {
          const int rloc = (mh << 4) + (lq << 2) + r4;
          const float z = (acc[(half << 1) + mh][ntl][r4] - cv) * alphav;
          s_sigT[col * 33 + rloc] = 1.f / (1.f + __expf(-z));
        }
      }
    }
    __syncthreads();

    // ---- Phase 3: tree leaf probs (in-register) -> p@A MFMA, K quarter kh.
    f32x4 acc2[4];
#pragma unroll
    for (int i = 0; i < 4; ++i) acc2[i] = {0.f, 0.f, 0.f, 0.f};

#define SV(node) s_sigT[(node) * 33 + arow]

#pragma unroll
    for (int ks = 0; ks < 2; ++ks) {
      const int lb = (kh << 6) + (ks << 5) + (lq << 3);
      float P = 1.f;
#pragma unroll
      for (int n = 0; n < 5; ++n) {
        const int node = (1 << n) - 1 + (lb >> (8 - n));
        const float s = SV(node);
        P *= ((lb >> (7 - n)) & 1) ? (1.f - s) : s;
      }
      const float s5 = SV(31 + (lb >> 3));
      const int n6 = 63 + (lb >> 2);
      const float s6a = SV(n6);
      const float s6b = SV(n6 + 1);
      const int n7 = 127 + (lb >> 1);
      const float s7_0 = SV(n7);
      const float s7_1 = SV(n7 + 1);
      const float s7_2 = SV(n7 + 2);
      const float s7_3 = SV(n7 + 3);
      const float q0 = P * s5, q1 = P - P * s5;
      const float r00 = q0 * s6a, r01 = q0 - q0 * s6a;
      const float r10 = q1 * s6b, r11 = q1 - q1 * s6b;
      float p[8];
      p[0] = r00 * s7_0; p[1] = r00 - p[0];
      p[2] = r01 * s7_1; p[3] = r01 - p[2];
      p[4] = r10 * s7_2; p[5] = r10 - p[4];
      p[6] = r11 * s7_3; p[7] = r11 - p[6];
      short8v pah, pal;
#pragma unroll
      for (int j = 0; j < 8; ++j) {
        const u16 h = f32_bf16(p[j]);
        pah[j] = (short)h;
        pal[j] = (short)f32_bf16(p[j] - bf16_f32(h));
      }
      const int ksg = (kh << 1) + ks;
#pragma unroll
      for (int nt = 0; nt < 4; ++nt) {
        const int fb = (((ksg << 2) + nt) << 9) + (lane << 3);
        const short8v bhv = *reinterpret_cast<const short8v*>(ATfh + fb);
        const short8v blv = *reinterpret_cast<const short8v*>(ATfl + fb);
        acc2[nt] = __builtin_amdgcn_mfma_f32_16x16x32_bf16(pah, bhv, acc2[nt], 0, 0, 0);
        acc2[nt] = __builtin_amdgcn_mfma_f32_16x16x32_bf16(pah, blv, acc2[nt], 0, 0, 0);
        acc2[nt] = __builtin_amdgcn_mfma_f32_16x16x32_bf16(pal, bhv, acc2[nt], 0, 0, 0);
      }
    }
    __syncthreads();  // s_sigT reads done

    // ---- Phase 4a: write K-quarter partials to s_part[kh][row][col] (pad 65)
#pragma unroll
    for (int nt = 0; nt < 4; ++nt)
#pragma unroll
      for (int r4 = 0; r4 < 4; ++r4)
        s_part[((kh << 5) + (mth << 4) + (lq << 2) + r4) * 65 + (nt << 4) + l15] = acc2[nt][r4];
    __syncthreads();

    // ---- Phase 4b+5: reduce 4 quarters, softmax, store. Thread row r = 4w+lq.
    {
      const int r = (w << 2) + lq;
      float v0 = 0.f, v1 = 0.f, v2 = 0.f, v3 = 0.f;
#pragma unroll
      for (int k2 = 0; k2 < 4; ++k2) {
        const float* pr = s_part + ((k2 << 5) + r) * 65 + l15;
        v0 += pr[0];
        v1 += pr[16];
        v2 += pr[32];
        v3 += pr[48];
      }
      float m = fmaxf(fmaxf(v0, v1), fmaxf(v2, v3));
#pragma unroll
      for (int d = 1; d < 16; d <<= 1) m = fmaxf(m, __shfl_xor(m, d, 64));
      float e0 = __expf(v0 - m), e1 = __expf(v1 - m), e2 = __expf(v2 - m), e3 = __expf(v3 - m);
      float ssum = e0 + e1 + e2 + e3;
#pragma unroll
      for (int d = 1; d < 16; d <<= 1) ssum += __shfl_xor(ssum, d, 64);
      const float inv = 1.f / ssum;
      float* op = out + (size_t)(row0 + (half << 5) + r) * ODIM + l15;
      op[0]  = e0 * inv;
      op[16] = e1 * inv;
      op[32] = e2 * inv;
      op[48] = e3 * inv;
    }
    __syncthreads();  // protect next half's s_sigT overwrite
  }
}

extern "C" void kernel_launch(void* const* d_in, const int* in_sizes, int n_in,
                              void* d_out, int out_size, void* d_ws, size_t ws_size,
                              hipStream_t stream) {
  const float* x      = (const float*)d_in[0];
  const float* layers = (const float*)d_in[1];
  const float* comp   = (const float*)d_in[2];
  const float* alpha  = (const float*)d_in[3];
  const float* aprobs = (const float*)d_in[4];
  float* out = (float*)d_out;

  const size_t wsplit = (size_t)131072;
  const size_t atsz   = (size_t)16384;
  if (ws_size < (2 * wsplit + 2 * atsz) * sizeof(u16)) return;

  u16* Wfh  = (u16*)d_ws;
  u16* Wfl  = Wfh + wsplit;
  u16* ATfh = Wfl + wsplit;
  u16* ATfl = ATfh + atsz;

  const int prep_items = 131072 + 16384;
  prep_kernel<<<dim3((prep_items + 255) / 256), dim3(256), 0, stream>>>(
      layers, aprobs, Wfh, Wfl, ATfh, ATfl);

  prolo_main<<<dim3(32768 / BM), dim3(512), 0, stream>>>(
      x, comp, alpha, Wfh, Wfl, ATfh, ATfl, out);
}

// Round 9
// 43.282 us; speedup vs baseline: 3.1987x; 1.7589x over previous
//
#include <hip/hip_runtime.h>

#define NODES 255
#define IN_DIM 512
#define ODIM 64
#define BM 64

typedef __attribute__((ext_vector_type(8))) short short8v;
typedef __attribute__((ext_vector_type(4))) float f32x4;
typedef unsigned short u16;
typedef unsigned int u32;

__device__ __forceinline__ u16 f32_bf16(float f) {
  u32 u = __builtin_bit_cast(u32, f);
  u += 0x7FFFu + ((u >> 16) & 1u);
  return (u16)(u >> 16);
}
__device__ __forceinline__ float bf16_f32(u16 h) {
  u32 u = ((u32)h) << 16;
  return __builtin_bit_cast(float, u);
}

// Fragment-linear pre-split (same as R5):
//  W: frag(kc 0..15, nb 0..15): elem(lane,j) = W[node=nb*16+(lane&15)][k=kc*32+(lane>>4)*8+j]
//     at linear ((kc*16+nb)*64+lane)*8+j
//  AT: frag(kc4 0..7, nb 0..3): elem(lane,j) = A[leaf=kc4*32+(lane>>4)*8+j][col=nb*16+(lane&15)]
//     at linear ((kc4*4+nb)*64+lane)*8+j
__global__ __launch_bounds__(256) void prep_kernel(
    const float* __restrict__ layers, const float* __restrict__ aprobs,
    u16* __restrict__ Wfh, u16* __restrict__ Wfl,
    u16* __restrict__ ATfh, u16* __restrict__ ATfl) {
  int id = blockIdx.x * 256 + threadIdx.x;
  if (id < 131072) {
    const int j = id & 7;
    const int lane = (id >> 3) & 63;
    const int nb = (id >> 9) & 15;
    const int kc = id >> 13;
    const int node = nb * 16 + (lane & 15);
    const int k = kc * 32 + ((lane >> 4) << 3) + j;
    const float v = (node < NODES) ? layers[node * IN_DIM + k] : 0.f;
    const u16 h = f32_bf16(v);
    Wfh[id] = h;
    Wfl[id] = f32_bf16(v - bf16_f32(h));
  } else if (id < 131072 + 16384) {
    const int t = id - 131072;
    const int j = t & 7;
    const int lane = (t >> 3) & 63;
    const int nb = (t >> 9) & 3;
    const int kc4 = t >> 11;
    const int c = nb * 16 + (lane & 15);
    const int leaf = kc4 * 32 + ((lane >> 4) << 3) + j;
    const float v = aprobs[leaf * ODIM + c];
    const u16 h = f32_bf16(v);
    ATfh[t] = h;
    ATfl[t] = f32_bf16(v - bf16_f32(h));
  }
}

// 512 threads (8 waves), BM=64 rows/block, grid 512, 2 blocks/CU (R5-proven).
// LDS 64KB union: phase 1 x dbuf bf16 hi/lo (32KB); phase 2+ s_sig f32[64][256];
// phase 4 partials f32[64][64].
__global__ __launch_bounds__(512, 4) void prolo_main(
    const float* __restrict__ x, const float* __restrict__ comp,
    const float* __restrict__ alpha,
    const u16* __restrict__ Wfh, const u16* __restrict__ Wfl,
    const u16* __restrict__ ATfh, const u16* __restrict__ ATfl,
    float* __restrict__ out) {
  __shared__ __align__(16) unsigned char smem[65536];
  float* s_sig = (float*)smem;
  u16* sA = (u16*)smem;  // buf b: hi at b*8192, lo at b*8192+4096 (u16 units)

  const int tid = threadIdx.x;
  const int lane = tid & 63;
  const int w = tid >> 6;
  const int l15 = lane & 15;
  const int lq = lane >> 4;
  const int row0 = blockIdx.x * BM;
  const float alphav = alpha[0];

  // prefetch comparators for phase 2
  const int col0 = (w << 5) + l15;
  const int col1 = col0 + 16;
  const float cv0 = (col0 < NODES) ? comp[col0] : 0.f;
  const float cv1 = (col1 < NODES) ? comp[col1] : 0.f;

  // ---------- Phase 1: z GEMM. Wave w owns nodes [32w, 32w+32), all 64 rows.
  f32x4 acc[4][2];
#pragma unroll
  for (int i = 0; i < 4; ++i)
#pragma unroll
    for (int j = 0; j < 2; ++j) acc[i][j] = {0.f, 0.f, 0.f, 0.f};

  const int srow = tid >> 3;            // staging row 0..63
  const int k0 = (tid & 7) << 3;        // staging k 0..56
  const int soff = srow * 64 + (k0 ^ ((srow & 7) << 3));
  const float* xbase = x + (size_t)(row0 + srow) * IN_DIM + k0;

  // 2-deep register prefetch (chunk = 64 k-columns; 8 floats/thread)
  f32x4 vA0 = *reinterpret_cast<const f32x4*>(xbase);
  f32x4 vA1 = *reinterpret_cast<const f32x4*>(xbase + 4);
  f32x4 vB0 = *reinterpret_cast<const f32x4*>(xbase + 64);
  f32x4 vB1 = *reinterpret_cast<const f32x4*>(xbase + 68);

#define STAGE_CHUNK(P0, P1, BUF)                                              \
  {                                                                           \
    u32* dh = reinterpret_cast<u32*>(sA + (BUF)*8192 + soff);                 \
    u32* dl = reinterpret_cast<u32*>(sA + (BUF)*8192 + 4096 + soff);          \
    float ff[8] = {P0[0], P0[1], P0[2], P0[3], P1[0], P1[1], P1[2], P1[3]};   \
    _Pragma("unroll") for (int j = 0; j < 4; ++j) {                           \
      u16 ha = f32_bf16(ff[2 * j]), hb = f32_bf16(ff[2 * j + 1]);             \
      u16 la = f32_bf16(ff[2 * j] - bf16_f32(ha));                            \
      u16 lb = f32_bf16(ff[2 * j + 1] - bf16_f32(hb));                        \
      dh[j] = (u32)ha | ((u32)hb << 16);                                      \
      dl[j] = (u32)la | ((u32)lb << 16);                                      \
    }                                                                         \
  }

  const int wfbase = (w << 10) + (lane << 3);

  // W-fragment register double-buffer: set = 4 frags (one kq half).
  short8v wbhA[2], wblA[2], wbhB[2], wblB[2];

#define LOADW(WH, WL, KS, KQ)                                                 \
  {                                                                           \
    _Pragma("unroll") for (int ntl = 0; ntl < 2; ++ntl) {                     \
      const int fb = ((((KS) << 1) + (KQ)) << 13) + wfbase + (ntl << 9);      \
      WH[ntl] = *reinterpret_cast<const short8v*>(Wfh + fb);                  \
      WL[ntl] = *reinterpret_cast<const short8v*>(Wfl + fb);                  \
    }                                                                         \
  }

#define CHALF(WH, WL, KQ, BUF)                                                \
  {                                                                           \
    _Pragma("unroll") for (int mt = 0; mt < 4; ++mt) {                        \
      const int r = (mt << 4) + l15;                                          \
      const int kk = ((KQ) << 5) + (lq << 3);                                 \
      const int aoff = r * 64 + (kk ^ ((r & 7) << 3));                        \
      const short8v ah = *reinterpret_cast<const short8v*>(sA + (BUF)*8192 + aoff);        \
      const short8v al = *reinterpret_cast<const short8v*>(sA + (BUF)*8192 + 4096 + aoff); \
      _Pragma("unroll") for (int ntl = 0; ntl < 2; ++ntl) {                   \
        acc[mt][ntl] = __builtin_amdgcn_mfma_f32_16x16x32_bf16(ah, WH[ntl], acc[mt][ntl], 0, 0, 0); \
        acc[mt][ntl] = __builtin_amdgcn_mfma_f32_16x16x32_bf16(ah, WL[ntl], acc[mt][ntl], 0, 0, 0); \
        acc[mt][ntl] = __builtin_amdgcn_mfma_f32_16x16x32_bf16(al, WH[ntl], acc[mt][ntl], 0, 0, 0); \
      }                                                                       \
    }                                                                         \
  }

  // prologue
  LOADW(wbhA, wblA, 0, 0);
  STAGE_CHUNK(vA0, vA1, 0);
  __syncthreads();

#pragma unroll
  for (int ks = 0; ks < 8; ++ks) {
    // x prefetch, 2 chunks ahead
    if (ks + 2 < 8) {
      const float* xp = xbase + (ks + 2) * 64;
      vA0 = *reinterpret_cast<const f32x4*>(xp);
      vA1 = *reinterpret_cast<const f32x4*>(xp + 4);
    }
    // issue W loads for this iter's second half before any compute
    LOADW(wbhB, wblB, ks, 1);
    // stage next x chunk (VALU + ds_write) — covers the W-load latency
    if (ks + 1 < 8) STAGE_CHUNK(vB0, vB1, ((ks + 1) & 1));

    // first half-compute (W prefetched last iter / prologue)
    CHALF(wbhA, wblA, 0, (ks & 1));
    // issue next iter's first-half W loads under the second half's MFMAs
    if (ks < 7) LOADW(wbhA, wblA, (ks + 1), 0);
    // second half-compute
    CHALF(wbhB, wblB, 1, (ks & 1));

    {
      f32x4 t0 = vA0, t1 = vA1;
      vA0 = vB0; vA1 = vB1;
      vB0 = t0;  vB1 = t1;
    }
    __syncthreads();
  }

  // ---------- Phase 2: sigmoid((z-c)*alpha) -> s_sig (col ^ (row&15) swizzle)
#pragma unroll
  for (int ntl = 0; ntl < 2; ++ntl) {
    const int col = (w << 5) + (ntl << 4) + l15;
    const float cv = ntl ? cv1 : cv0;
#pragma unroll
    for (int mt = 0; mt < 4; ++mt) {
#pragma unroll
      for (int r4 = 0; r4 < 4; ++r4) {
        const int r = (mt << 4) + (lq << 2) + r4;
        const float z = (acc[mt][ntl][r4] - cv) * alphav;
        const float s = 1.f / (1.f + __expf(-z));
        s_sig[(r << 8) + (col ^ (r & 15))] = s;
      }
    }
  }
  __syncthreads();

  // ---------- Phase 3+4: in-register leaf probs feeding p@A MFMA.
  const int mt3 = w & 3;
  const int kh = w >> 2;
  const int arow = (mt3 << 4) + l15;
  const float* srow_p = s_sig + (arow << 8);
  const int sw = arow & 15;

  f32x4 acc2[4];
#pragma unroll
  for (int i = 0; i < 4; ++i) acc2[i] = {0.f, 0.f, 0.f, 0.f};

#pragma unroll
  for (int ks = 0; ks < 4; ++ks) {
    // hoist all 8 AT fragment loads to the top — tree walk covers L2 latency
    short8v bhv[4], blv[4];
#pragma unroll
    for (int nt = 0; nt < 4; ++nt) {
      const int fb = ((((kh << 2) + ks) << 2) + nt) * 512 + (lane << 3);
      bhv[nt] = *reinterpret_cast<const short8v*>(ATfh + fb);
      blv[nt] = *reinterpret_cast<const short8v*>(ATfl + fb);
    }

    const int lb = (kh << 7) + (ks << 5) + (lq << 3);
    float P = 1.f;
#pragma unroll
    for (int n = 0; n < 5; ++n) {
      const int node = (1 << n) - 1 + (lb >> (8 - n));
      const float s = srow_p[node ^ sw];
      P *= ((lb >> (7 - n)) & 1) ? (1.f - s) : s;
    }
    const float s5 = srow_p[(31 + (lb >> 3)) ^ sw];
    const int n6 = 63 + (lb >> 2);
    const float s6a = srow_p[n6 ^ sw];
    const float s6b = srow_p[(n6 + 1) ^ sw];
    const int n7 = 127 + (lb >> 1);
    const float s7_0 = srow_p[n7 ^ sw];
    const float s7_1 = srow_p[(n7 + 1) ^ sw];
    const float s7_2 = srow_p[(n7 + 2) ^ sw];
    const float s7_3 = srow_p[(n7 + 3) ^ sw];
    const float q0 = P * s5, q1 = P - P * s5;
    const float r00 = q0 * s6a, r01 = q0 - q0 * s6a;
    const float r10 = q1 * s6b, r11 = q1 - q1 * s6b;
    float p[8];
    p[0] = r00 * s7_0; p[1] = r00 - p[0];
    p[2] = r01 * s7_1; p[3] = r01 - p[2];
    p[4] = r10 * s7_2; p[5] = r10 - p[4];
    p[6] = r11 * s7_3; p[7] = r11 - p[6];
    short8v pah, pal;
#pragma unroll
    for (int j = 0; j < 8; ++j) {
      const u16 h = f32_bf16(p[j]);
      pah[j] = (short)h;
      pal[j] = (short)f32_bf16(p[j] - bf16_f32(h));
    }
#pragma unroll
    for (int nt = 0; nt < 4; ++nt) {
      acc2[nt] = __builtin_amdgcn_mfma_f32_16x16x32_bf16(pah, bhv[nt], acc2[nt], 0, 0, 0);
      acc2[nt] = __builtin_amdgcn_mfma_f32_16x16x32_bf16(pah, blv[nt], acc2[nt], 0, 0, 0);
      acc2[nt] = __builtin_amdgcn_mfma_f32_16x16x32_bf16(pal, bhv[nt], acc2[nt], 0, 0, 0);
    }
  }
  __syncthreads();  // all waves done reading s_sig

  // K-half combine via smem partials (aliases s_sig, now dead)
  float* part = (float*)smem;  // [64][64] f32
  if (kh == 1) {
#pragma unroll
    for (int nt = 0; nt < 4; ++nt)
#pragma unroll
      for (int r4 = 0; r4 < 4; ++r4)
        part[(((mt3 << 4) + (lq << 2) + r4) << 6) + (nt << 4) + l15] = acc2[nt][r4];
  }
  __syncthreads();

  if (kh == 0) {
#pragma unroll
    for (int r4 = 0; r4 < 4; ++r4) {
      const int rloc = (mt3 << 4) + (lq << 2) + r4;
      float v0 = acc2[0][r4] + part[(rloc << 6) + l15];
      float v1 = acc2[1][r4] + part[(rloc << 6) + 16 + l15];
      float v2 = acc2[2][r4] + part[(rloc << 6) + 32 + l15];
      float v3 = acc2[3][r4] + part[(rloc << 6) + 48 + l15];
      float m = fmaxf(fmaxf(v0, v1), fmaxf(v2, v3));
#pragma unroll
      for (int d = 1; d < 16; d <<= 1) m = fmaxf(m, __shfl_xor(m, d, 64));
      float e0 = __expf(v0 - m), e1 = __expf(v1 - m), e2 = __expf(v2 - m), e3 = __expf(v3 - m);
      float ssum = e0 + e1 + e2 + e3;
#pragma unroll
      for (int d = 1; d < 16; d <<= 1) ssum += __shfl_xor(ssum, d, 64);
      const float inv = 1.f / ssum;
      float* op = out + (size_t)(row0 + rloc) * ODIM + l15;
      op[0] = e0 * inv;
      op[16] = e1 * inv;
      op[32] = e2 * inv;
      op[48] = e3 * inv;
    }
  }
}

extern "C" void kernel_launch(void* const* d_in, const int* in_sizes, int n_in,
                              void* d_out, int out_size, void* d_ws, size_t ws_size,
                              hipStream_t stream) {
  const float* x      = (const float*)d_in[0];
  const float* layers = (const float*)d_in[1];
  const float* comp   = (const float*)d_in[2];
  const float* alpha  = (const float*)d_in[3];
  const float* aprobs = (const float*)d_in[4];
  float* out = (float*)d_out;

  const size_t wsplit = (size_t)131072;
  const size_t atsz   = (size_t)16384;
  if (ws_size < (2 * wsplit + 2 * atsz) * sizeof(u16)) return;

  u16* Wfh  = (u16*)d_ws;
  u16* Wfl  = Wfh + wsplit;
  u16* ATfh = Wfl + wsplit;
  u16* ATfl = ATfh + atsz;

  const int prep_items = 131072 + 16384;
  prep_kernel<<<dim3((prep_items + 255) / 256), dim3(256), 0, stream>>>(
      layers, aprobs, Wfh, Wfl, ATfh, ATfl);

  prolo_main<<<dim3(32768 / BM), dim3(512), 0, stream>>>(
      x, comp, alpha, Wfh, Wfl, ATfh, ATfl, out);
}